// Round 8
// baseline (188.339 us; speedup 1.0000x reference)
//
#include <hip/hip_runtime.h>
#include <hip/hip_bf16.h>
#include <cstdint>
#include <cstddef>

#define BDIM 64
#define SDIM 512
#define HDIM 1024
#define MTOT (BDIM * SDIM)  // 32768

typedef __attribute__((ext_vector_type(8))) short short8;
typedef __attribute__((ext_vector_type(4))) float f32x4;

__device__ __forceinline__ unsigned int cvt2(float a, float b) {
  unsigned int r;
  asm("v_cvt_pk_bf16_f32 %0, %1, %2" : "=v"(r) : "v"(a), "v"(b));
  return r;
}

__device__ __forceinline__ void gld_lds16(const void* g, void* l) {
  __builtin_amdgcn_global_load_lds(
      (const __attribute__((address_space(1))) unsigned int*)g,
      (__attribute__((address_space(3))) unsigned int*)l, 16, 0, 0);
}

// tanh via hw exp2 + rcp: tanh(x) = 1 - 2/(e^{2x}+1). |err| ~1e-6, correct sat.
__device__ __forceinline__ float fast_tanh(float x) {
  const float e = __builtin_exp2f(x * 2.88539008f);  // 2*log2(e)
  return 1.0f - 2.0f * __builtin_amdgcn_rcpf(e + 1.0f);
}

// ---------- shared prep bodies ----------
__device__ __forceinline__ void w2_body(const float* __restrict__ W,
                                        char* __restrict__ w2s, int bx, int tid) {
  const int n = bx * 2 + (tid >> 7);
  const int g = tid & 127;
  const int kt = g >> 3, gi = g & 7;
  const float* src = W + (size_t)n * 2048 + 1024 + g * 8;
  const float4 f0 = *reinterpret_cast<const float4*>(src);
  const float4 f1 = *reinterpret_cast<const float4*>(src + 4);
  uint4 u = make_uint4(cvt2(f0.x, f0.y), cvt2(f0.z, f0.w),
                       cvt2(f1.x, f1.y), cvt2(f1.z, f1.w));
  const int nblk = n >> 7, row = n & 127;
  const size_t off = ((size_t)(nblk * 16 + kt) * 128 + row) * 128 +
                     (size_t)(gi ^ (row & 7)) * 16;
  *reinterpret_cast<uint4*>(w2s + off) = u;
}

__device__ __forceinline__ void a_body(const float* __restrict__ hidden,
                                       const float* __restrict__ W,
                                       const float* __restrict__ bias,
                                       float* __restrict__ A, float* hl,
                                       int bx, int tid) {
  const int hc = bx & 3, b = bx >> 2;
  *reinterpret_cast<float4*>(&hl[tid * 4]) =
      *reinterpret_cast<const float4*>(hidden + (size_t)b * HDIM + tid * 4);
  __syncthreads();
  const int h = hc * 256 + tid;
  const float* wr = W + (size_t)h * 2048;
  float a0 = 0.f, a1 = 0.f, a2 = 0.f, a3 = 0.f;
  for (int k = 0; k < HDIM; k += 16) {
    const float4 w0 = *reinterpret_cast<const float4*>(wr + k);
    const float4 w1 = *reinterpret_cast<const float4*>(wr + k + 4);
    const float4 w2 = *reinterpret_cast<const float4*>(wr + k + 8);
    const float4 w3 = *reinterpret_cast<const float4*>(wr + k + 12);
    a0 += w0.x * hl[k]      + w0.y * hl[k + 1]  + w0.z * hl[k + 2]  + w0.w * hl[k + 3];
    a1 += w1.x * hl[k + 4]  + w1.y * hl[k + 5]  + w1.z * hl[k + 6]  + w1.w * hl[k + 7];
    a2 += w2.x * hl[k + 8]  + w2.y * hl[k + 9]  + w2.z * hl[k + 10] + w2.w * hl[k + 11];
    a3 += w3.x * hl[k + 12] + w3.y * hl[k + 13] + w3.z * hl[k + 14] + w3.w * hl[k + 15];
  }
  A[(size_t)b * HDIM + h] = bias[h] + ((a0 + a1) + (a2 + a3));
}

// ---- fused prep: [0,2048) enc->bf16 swizzled | [2048,2560) W2 | [2560,2816) A ----
__global__ __launch_bounds__(256) void prep_all_kernel(const float* __restrict__ enc,
                                                       const float* __restrict__ W,
                                                       const float* __restrict__ hidden,
                                                       const float* __restrict__ bias,
                                                       char* __restrict__ enc16,
                                                       char* __restrict__ w2s,
                                                       float* __restrict__ A) {
  __shared__ float hl[HDIM];
  const int bid = blockIdx.x;
  const int tid = threadIdx.x;
  if (bid < 2048) {
    const int kt = tid >> 4;
    const int gi = (tid >> 1) & 7;
    const int half = (tid & 1) * 8;
    const int row_base = bid * 16;
#pragma unroll 4
    for (int i = 0; i < 16; ++i) {
      const int grow = row_base + i;
      const float4 f = *reinterpret_cast<const float4*>(enc + (size_t)grow * 1024 + tid * 4);
      const uint2 u = make_uint2(cvt2(f.x, f.y), cvt2(f.z, f.w));
      const int strip = grow >> 7, rr = grow & 127;
      char* dst = enc16 + ((size_t)(strip * 16 + kt) * 16384) + rr * 128 +
                  ((gi ^ (rr & 7)) * 16) + half;
      *reinterpret_cast<uint2*>(dst) = u;
    }
  } else if (bid < 2560) {
    w2_body(W, w2s, bid - 2048, tid);
  } else {
    a_body(hidden, W, bias, A, hl, bid - 2560, tid);
  }
}

// ---- small prep (fallback): [0,512) W2 | [512,768) A ----
__global__ __launch_bounds__(256) void prep_small_kernel(const float* __restrict__ W,
                                                         const float* __restrict__ hidden,
                                                         const float* __restrict__ bias,
                                                         char* __restrict__ w2s,
                                                         float* __restrict__ A) {
  __shared__ float hl[HDIM];
  const int bid = blockIdx.x;
  const int tid = threadIdx.x;
  if (bid < 512) w2_body(W, w2s, bid, tid);
  else a_body(hidden, W, bias, A, hl, bid - 512, tid);
}

// ---- main GEMM: 256x256, 8 waves, BK=64, dbuf, per-phase barrier + counted vmcnt ----
__global__ __launch_bounds__(512, 2) void gemm8_kernel(const char* __restrict__ enc16,
                                                       const char* __restrict__ w2s,
                                                       const float* __restrict__ A,
                                                       const float* __restrict__ v,
                                                       float* __restrict__ sp) {
  __shared__ __align__(16) unsigned short As[2][2][128][64];  // 64 KB
  __shared__ __align__(16) unsigned short Bs[2][2][128][64];  // 64 KB
  __shared__ float red4[4][256];                              // 4 KB

  const int bid = blockIdx.x;
  const int lg = (bid & 7) * 64 + (bid >> 3);  // XCD swizzle, 512 % 8 == 0
  const int nblk = lg & 3, mstrip = lg >> 2;
  const int m0 = mstrip * 256, n0 = nblk * 256;
  const int b = m0 >> 9;

  const int tid = threadIdx.x;
  const int w = tid >> 6, l = tid & 63;
  const int wm = w >> 2, wn = w & 3;  // 2 x 4 wave grid
  const int lr = l & 15, lk = l >> 4;

  f32x4 acc[8][4];
#pragma unroll
  for (int i = 0; i < 8; ++i)
#pragma unroll
    for (int j = 0; j < 4; ++j) acc[i][j] = (f32x4){0.f, 0.f, 0.f, 0.f};

  const char* aT0 = enc16 + (size_t)((mstrip * 2 + 0) * 16) * 16384;
  const char* aT1 = enc16 + (size_t)((mstrip * 2 + 1) * 16) * 16384;
  const char* bT0 = w2s + (size_t)((nblk * 2 + 0) * 16) * 16384;
  const char* bT1 = w2s + (size_t)((nblk * 2 + 1) * 16) * 16384;

  const int wb = w * 1024;
  const int lofs = l * 16;

#define STG8(srcp, dstp) \
  gld_lds16((const char*)(srcp) + wb + lofs, (char*)(dstp) + wb)
#define VMW(N) asm volatile("s_waitcnt vmcnt(" #N ")" ::: "memory")
#define LGKM0 asm volatile("s_waitcnt lgkmcnt(0)" ::: "memory")
#define SBAR() do { __builtin_amdgcn_s_barrier(); __builtin_amdgcn_sched_barrier(0); } while (0)

  // prologue: stage kt=0 into buf0, slot order Ab0 | Bh0 | Bh1 | Ab1
  STG8(aT0, &As[0][0][0][0]);  STG8(aT1, &As[0][1][0][0]);
  STG8(bT0, &Bs[0][0][0][0]);  STG8((const char*)bT0 + 8192, (char*)&Bs[0][0][0][0] + 8192);
  STG8(bT1, &Bs[0][1][0][0]);  STG8((const char*)bT1 + 8192, (char*)&Bs[0][1][0][0] + 8192);
  STG8((const char*)aT0 + 8192, (char*)&As[0][0][0][0] + 8192);
  STG8((const char*)aT1 + 8192, (char*)&As[0][1][0][0] + 8192);

  const int gax = lr & 7;

  for (int kt = 0; kt < 16; ++kt) {
    const int cur = kt & 1, nxt = cur ^ 1;
    const size_t ko = (size_t)(kt + 1) * 16384;
    const bool pf = (kt < 15);
    const char* Ah = (const char*)&As[cur][wm][0][0];
    const char* Bh = (const char*)&Bs[cur][wn >> 1][0][0];
    char* A0n = (char*)&As[nxt][0][0][0];
    char* A1n = (char*)&As[nxt][1][0][0];
    char* B0n = (char*)&Bs[nxt][0][0][0];
    char* B1n = (char*)&Bs[nxt][1][0][0];
    const int brow0 = (wn & 1) * 64;
    const int gq0 = (lk ^ gax) * 16;
    const int gq1 = ((4 + lk) ^ gax) * 16;

    short8 af[4], bf[4];

    // ph0 (ks0,mg0): consumes A(wm,band0)+B(own); stages A band0 of kt+1
    VMW(2);
    SBAR();
    if (pf) { STG8(aT0 + ko, A0n); STG8(aT1 + ko, A1n); }
#pragma unroll
    for (int f = 0; f < 4; ++f) {
      bf[f] = *reinterpret_cast<const short8*>(Bh + (brow0 + f * 16 + lr) * 128 + gq0);
      af[f] = *reinterpret_cast<const short8*>(Ah + (f * 16 + lr) * 128 + gq0);
    }
    LGKM0; __builtin_amdgcn_sched_barrier(0);
    __builtin_amdgcn_s_setprio(1);
#pragma unroll
    for (int fm = 0; fm < 4; ++fm)
#pragma unroll
      for (int fn = 0; fn < 4; ++fn)
        acc[fm][fn] = __builtin_amdgcn_mfma_f32_16x16x32_bf16(af[fm], bf[fn], acc[fm][fn], 0, 0, 0);
    __builtin_amdgcn_s_setprio(0);

    // ph1 (ks0,mg1): consumes A(wm,band1); stages B half0
    if (pf) { VMW(2); } else { VMW(0); }
    SBAR();
    if (pf) { STG8(bT0 + ko, B0n); STG8((const char*)bT0 + ko + 8192, B0n + 8192); }
#pragma unroll
    for (int f = 0; f < 4; ++f)
      af[f] = *reinterpret_cast<const short8*>(Ah + (64 + f * 16 + lr) * 128 + gq0);
    LGKM0; __builtin_amdgcn_sched_barrier(0);
    __builtin_amdgcn_s_setprio(1);
#pragma unroll
    for (int fm = 0; fm < 4; ++fm)
#pragma unroll
      for (int fn = 0; fn < 4; ++fn)
        acc[4 + fm][fn] = __builtin_amdgcn_mfma_f32_16x16x32_bf16(af[fm], bf[fn], acc[4 + fm][fn], 0, 0, 0);
    __builtin_amdgcn_s_setprio(0);

    // ph2 (ks1,mg0): re-reads; stages B half1
    VMW(4);
    SBAR();
    if (pf) { STG8(bT1 + ko, B1n); STG8((const char*)bT1 + ko + 8192, B1n + 8192); }
#pragma unroll
    for (int f = 0; f < 4; ++f) {
      bf[f] = *reinterpret_cast<const short8*>(Bh + (brow0 + f * 16 + lr) * 128 + gq1);
      af[f] = *reinterpret_cast<const short8*>(Ah + (f * 16 + lr) * 128 + gq1);
    }
    LGKM0; __builtin_amdgcn_sched_barrier(0);
    __builtin_amdgcn_s_setprio(1);
#pragma unroll
    for (int fm = 0; fm < 4; ++fm)
#pragma unroll
      for (int fn = 0; fn < 4; ++fn)
        acc[fm][fn] = __builtin_amdgcn_mfma_f32_16x16x32_bf16(af[fm], bf[fn], acc[fm][fn], 0, 0, 0);
    __builtin_amdgcn_s_setprio(0);

    // ph3 (ks1,mg1): re-reads; stages A band1 of kt+1
    VMW(6);
    SBAR();
    if (pf) {
      STG8((const char*)aT0 + ko + 8192, A0n + 8192);
      STG8((const char*)aT1 + ko + 8192, A1n + 8192);
    }
#pragma unroll
    for (int f = 0; f < 4; ++f)
      af[f] = *reinterpret_cast<const short8*>(Ah + (64 + f * 16 + lr) * 128 + gq1);
    LGKM0; __builtin_amdgcn_sched_barrier(0);
    __builtin_amdgcn_s_setprio(1);
#pragma unroll
    for (int fm = 0; fm < 4; ++fm)
#pragma unroll
      for (int fn = 0; fn < 4; ++fn)
        acc[4 + fm][fn] = __builtin_amdgcn_mfma_f32_16x16x32_bf16(af[fm], bf[fn], acc[4 + fm][fn], 0, 0, 0);
    __builtin_amdgcn_s_setprio(0);
  }
#undef STG8
#undef VMW
#undef LGKM0
#undef SBAR

  // epilogue: partial[m] = sum_n v[n] * tanh(C[m,n] + A[b,n])
  float a_n[4], v_n[4];
#pragma unroll
  for (int fn = 0; fn < 4; ++fn) {
    const int n = wn * 64 + fn * 16 + lr;
    a_n[fn] = A[(size_t)b * HDIM + n0 + n];
    v_n[fn] = v[n0 + n];
  }
#pragma unroll
  for (int fm8 = 0; fm8 < 8; ++fm8) {
#pragma unroll
    for (int r = 0; r < 4; ++r) {
      float s = 0.f;
#pragma unroll
      for (int fn = 0; fn < 4; ++fn)
        s += v_n[fn] * fast_tanh(acc[fm8][fn][r] + a_n[fn]);
      s += __shfl_xor(s, 1);
      s += __shfl_xor(s, 2);
      s += __shfl_xor(s, 4);
      s += __shfl_xor(s, 8);
      if (lr == 0) red4[wn][wm * 128 + fm8 * 16 + lk * 4 + r] = s;
    }
  }
  __syncthreads();
  if (tid < 256) {
    const float ssum = red4[0][tid] + red4[1][tid] + red4[2][tid] + red4[3][tid];
    sp[(size_t)nblk * MTOT + m0 + tid] = ssum;
  }
}

// ---- softmax over s (512) per b; sums 4 partials ----
__global__ __launch_bounds__(512) void softmax4_kernel(const float* __restrict__ sp,
                                                       float* __restrict__ wts) {
  const int b = blockIdx.x, s = threadIdx.x;
  float sc = 0.f;
#pragma unroll
  for (int j = 0; j < 4; ++j) sc += sp[(size_t)j * MTOT + b * SDIM + s];
  float m = sc;
#pragma unroll
  for (int d = 1; d < 64; d <<= 1) m = fmaxf(m, __shfl_xor(m, d));
  __shared__ float redm[8], reds[8];
  if ((s & 63) == 0) redm[s >> 6] = m;
  __syncthreads();
  m = redm[0];
#pragma unroll
  for (int j = 1; j < 8; ++j) m = fmaxf(m, redm[j]);
  const float e = expf(sc - m);
  float sum = e;
#pragma unroll
  for (int d = 1; d < 64; d <<= 1) sum += __shfl_xor(sum, d);
  if ((s & 63) == 0) reds[s >> 6] = sum;
  __syncthreads();
  float tot = 0.f;
#pragma unroll
  for (int j = 0; j < 8; ++j) tot += reds[j];
  wts[(size_t)b * SDIM + s] = e / tot;
}

// ---- context[b,h] = sum_s w[b,s]*enc[b,s,h]; float2/lane (512B wave segments) ----
__global__ __launch_bounds__(256) void context_kernel(const float* __restrict__ enc,
                                                      const float* __restrict__ wts,
                                                      float* __restrict__ ctx) {
  const int hc = blockIdx.x;  // 0..1
  const int b  = blockIdx.y;  // 0..63
  const int t  = threadIdx.x;
  __shared__ float wl[SDIM];
  wl[t] = wts[(size_t)b * SDIM + t];
  wl[t + 256] = wts[(size_t)b * SDIM + 256 + t];
  __syncthreads();
  const int h = hc * 512 + t * 2;
  const float* e0 = enc + (size_t)b * SDIM * HDIM + h;
  float x0 = 0.f, y0 = 0.f, x1 = 0.f, y1 = 0.f;
  for (int s = 0; s < SDIM; s += 2) {
    const float2 v0 = *reinterpret_cast<const float2*>(e0 + (size_t)s * HDIM);
    const float2 v1 = *reinterpret_cast<const float2*>(e0 + (size_t)(s + 1) * HDIM);
    x0 += wl[s] * v0.x;     y0 += wl[s] * v0.y;
    x1 += wl[s + 1] * v1.x; y1 += wl[s + 1] * v1.y;
  }
  ctx[(size_t)b * HDIM + h]     = x0 + x1;
  ctx[(size_t)b * HDIM + h + 1] = y0 + y1;
}

// ================== fallback (small ws): r6-proven fused-convert GEMM ==================
__global__ __launch_bounds__(512, 2) void gemm8f_kernel(const float* __restrict__ enc,
                                                        const char* __restrict__ w2s,
                                                        const float* __restrict__ A,
                                                        const float* __restrict__ v,
                                                        float* __restrict__ sp) {
  __shared__ __align__(16) unsigned short As[2][2][128][64];
  __shared__ __align__(16) unsigned short Bs[2][2][128][64];
  __shared__ float red4[4][256];

  const int bid = blockIdx.x;
  const int lg = (bid & 7) * 64 + (bid >> 3);
  const int nblk = lg & 3, mstrip = lg >> 2;
  const int m0 = mstrip * 256, n0 = nblk * 256;
  const int b = m0 >> 9;
  const int tid = threadIdx.x;
  const int w = tid >> 6, l = tid & 63;
  const int wm = w >> 2, wn = w & 3;
  const int lr = l & 15, lk = l >> 4;

  f32x4 acc[8][4];
#pragma unroll
  for (int i = 0; i < 8; ++i)
#pragma unroll
    for (int j = 0; j < 4; ++j) acc[i][j] = (f32x4){0.f, 0.f, 0.f, 0.f};

  const int row0 = tid >> 3, g0 = tid & 7;
  const float* encA = enc + (size_t)m0 * HDIM + g0 * 8;
  const char* bT0 = w2s + (size_t)((nblk * 2 + 0) * 16) * 16384;
  const char* bT1 = w2s + (size_t)((nblk * 2 + 1) * 16) * 16384;
  const int wbase = w * 1024;
  const int lofs = l * 16;

#define STAGE_B(srcp, dstp)                                                \
  do {                                                                     \
    gld_lds16((const char*)(srcp) + wbase + lofs, (char*)(dstp) + wbase);  \
    gld_lds16((const char*)(srcp) + 8192 + wbase + lofs,                   \
              (char*)(dstp) + 8192 + wbase);                               \
  } while (0)
#define LOAD_A(pfv, ii, ktv)                                                 \
  do {                                                                      \
    const float* s_ = encA + (size_t)(row0 + (ii) * 64) * HDIM + (ktv) * 64; \
    pfv[2 * (ii)]     = *reinterpret_cast<const float4*>(s_);               \
    pfv[2 * (ii) + 1] = *reinterpret_cast<const float4*>(s_ + 4);           \
  } while (0)

  float4 pf[8];
  LOAD_A(pf, 0, 0); LOAD_A(pf, 1, 0); LOAD_A(pf, 2, 0); LOAD_A(pf, 3, 0);
  STAGE_B(bT0, &Bs[0][0][0][0]);
  STAGE_B(bT1, &Bs[0][1][0][0]);

  const int gax = lr & 7;

  for (int kt = 0; kt < 16; ++kt) {
    const int cur = kt & 1, nxt = cur ^ 1;
#pragma unroll
    for (int i = 0; i < 4; ++i) {
      const int row = row0 + i * 64;
      uint4 u = make_uint4(cvt2(pf[2 * i].x, pf[2 * i].y),
                           cvt2(pf[2 * i].z, pf[2 * i].w),
                           cvt2(pf[2 * i + 1].x, pf[2 * i + 1].y),
                           cvt2(pf[2 * i + 1].z, pf[2 * i + 1].w));
      char* dst = reinterpret_cast<char*>(&As[cur][row >> 7][0][0]);
      *reinterpret_cast<uint4*>(dst + (row & 127) * 128 + ((g0 ^ (row & 7)) * 16)) = u;
    }
    __syncthreads();

    const bool pfb = (kt < 15);
    const char* Ah = (const char*)&As[cur][wm][0][0];
    const char* Bh = (const char*)&Bs[cur][wn >> 1][0][0];
    const int brow0 = (wn & 1) * 64;

    short8 af[4], bf[4];
#pragma unroll
    for (int ks = 0; ks < 2; ++ks) {
      const int gq = ((ks * 4 + lk) ^ gax) * 16;
#pragma unroll
      for (int mg = 0; mg < 2; ++mg) {
        if (pfb) {
          const int ph = ks * 2 + mg;
          if (ph == 0)      { LOAD_A(pf, 0, kt + 1); LOAD_A(pf, 1, kt + 1); }
          else if (ph == 1) { LOAD_A(pf, 2, kt + 1); LOAD_A(pf, 3, kt + 1); }
          else if (ph == 2) { STAGE_B(bT0 + (size_t)(kt + 1) * 16384, &Bs[nxt][0][0][0]); }
          else              { STAGE_B(bT1 + (size_t)(kt + 1) * 16384, &Bs[nxt][1][0][0]); }
        }
        if (mg == 0) {
#pragma unroll
          for (int f = 0; f < 4; ++f)
            bf[f] = *reinterpret_cast<const short8*>(
                Bh + (brow0 + f * 16 + lr) * 128 + gq);
        }
#pragma unroll
        for (int f = 0; f < 4; ++f)
          af[f] = *reinterpret_cast<const short8*>(
              Ah + ((mg * 4 + f) * 16 + lr) * 128 + gq);
        asm volatile("s_waitcnt lgkmcnt(0)" ::: "memory");
        __builtin_amdgcn_sched_barrier(0);
        __builtin_amdgcn_s_setprio(1);
#pragma unroll
        for (int fm = 0; fm < 4; ++fm)
#pragma unroll
          for (int fn = 0; fn < 4; ++fn)
            acc[mg * 4 + fm][fn] = __builtin_amdgcn_mfma_f32_16x16x32_bf16(
                af[fm], bf[fn], acc[mg * 4 + fm][fn], 0, 0, 0);
        __builtin_amdgcn_s_setprio(0);
      }
    }
  }
#undef STAGE_B
#undef LOAD_A

  float a_n[4], v_n[4];
#pragma unroll
  for (int fn = 0; fn < 4; ++fn) {
    const int n = wn * 64 + fn * 16 + lr;
    a_n[fn] = A[(size_t)b * HDIM + n0 + n];
    v_n[fn] = v[n0 + n];
  }
#pragma unroll
  for (int fm8 = 0; fm8 < 8; ++fm8) {
#pragma unroll
    for (int r = 0; r < 4; ++r) {
      float s = 0.f;
#pragma unroll
      for (int fn = 0; fn < 4; ++fn)
        s += v_n[fn] * fast_tanh(acc[fm8][fn][r] + a_n[fn]);
      s += __shfl_xor(s, 1);
      s += __shfl_xor(s, 2);
      s += __shfl_xor(s, 4);
      s += __shfl_xor(s, 8);
      if (lr == 0) red4[wn][wm * 128 + fm8 * 16 + lk * 4 + r] = s;
    }
  }
  __syncthreads();
  if (tid < 256) {
    const float ssum = red4[0][tid] + red4[1][tid] + red4[2][tid] + red4[3][tid];
    sp[(size_t)nblk * MTOT + m0 + tid] = ssum;
  }
}

extern "C" void kernel_launch(void* const* d_in, const int* in_sizes, int n_in,
                              void* d_out, int out_size, void* d_ws, size_t ws_size,
                              hipStream_t stream) {
  const float* hidden = (const float*)d_in[0];
  const float* enc    = (const float*)d_in[1];
  const float* W      = (const float*)d_in[2];
  const float* bias   = (const float*)d_in[3];
  const float* v      = (const float*)d_in[4];

  float* ctx = (float*)d_out;                // [64*1024] context
  float* wts = (float*)d_out + BDIM * HDIM;  // [64*512] attention weights

  char* ws = (char*)d_ws;
  const size_t ENC16_BYTES = (size_t)64 * 1024 * 1024;
  const size_t BIG_NEED = ENC16_BYTES + 2 * 1024 * 1024 + 256 * 1024 + 512 * 1024;

  if (ws_size >= BIG_NEED) {
    char* enc16 = ws;
    char* w2s   = ws + ENC16_BYTES;
    float* A    = (float*)(ws + ENC16_BYTES + 2 * 1024 * 1024);
    float* sp   = (float*)(ws + ENC16_BYTES + 2 * 1024 * 1024 + 256 * 1024);
    hipLaunchKernelGGL(prep_all_kernel, dim3(2816), dim3(256), 0, stream,
                       enc, W, hidden, bias, enc16, w2s, A);
    hipLaunchKernelGGL(gemm8_kernel, dim3(512), dim3(512), 0, stream, enc16, w2s, A, v, sp);
    hipLaunchKernelGGL(softmax4_kernel, dim3(64), dim3(512), 0, stream, sp, wts);
    hipLaunchKernelGGL(context_kernel, dim3(2, 64), dim3(256), 0, stream, enc, wts, ctx);
  } else {
    char* w2s = ws;
    float* A  = (float*)(ws + (size_t)2 * 1024 * 1024);
    float* sp = (float*)(ws + (size_t)2 * 1024 * 1024 + 256 * 1024);
    hipLaunchKernelGGL(prep_small_kernel, dim3(768), dim3(256), 0, stream,
                       W, hidden, bias, w2s, A);
    hipLaunchKernelGGL(gemm8f_kernel, dim3(512), dim3(512), 0, stream, enc, w2s, A, v, sp);
    hipLaunchKernelGGL(softmax4_kernel, dim3(64), dim3(512), 0, stream, sp, wts);
    hipLaunchKernelGGL(context_kernel, dim3(2, 64), dim3(256), 0, stream, enc, wts, ctx);
  }
}

// Round 9
// 149.644 us; speedup vs baseline: 1.2586x; 1.2586x over previous
//
#include <hip/hip_runtime.h>
#include <hip/hip_bf16.h>
#include <cstdint>
#include <cstddef>

#define BDIM 64
#define SDIM 512
#define HDIM 1024
#define MTOT (BDIM * SDIM)  // 32768

typedef __attribute__((ext_vector_type(8))) short short8;
typedef __attribute__((ext_vector_type(4))) float f32x4;

__device__ __forceinline__ unsigned int cvt2(float a, float b) {
  unsigned int r;
  asm("v_cvt_pk_bf16_f32 %0, %1, %2" : "=v"(r) : "v"(a), "v"(b));
  return r;
}

__device__ __forceinline__ void gld_lds16(const void* g, void* l) {
  __builtin_amdgcn_global_load_lds(
      (const __attribute__((address_space(1))) unsigned int*)g,
      (__attribute__((address_space(3))) unsigned int*)l, 16, 0, 0);
}

// tanh via hw exp2 + rcp: tanh(x) = 1 - 2/(e^{2x}+1). |err| ~1e-6, correct sat.
__device__ __forceinline__ float fast_tanh(float x) {
  const float e = __builtin_exp2f(x * 2.88539008f);  // 2*log2(e)
  return 1.0f - 2.0f * __builtin_amdgcn_rcpf(e + 1.0f);
}

// ---------- prep bodies (r6/r8-proven) ----------
__device__ __forceinline__ void w2_body(const float* __restrict__ W,
                                        char* __restrict__ w2s, int bx, int tid) {
  const int n = bx * 2 + (tid >> 7);
  const int g = tid & 127;
  const int kt = g >> 3, gi = g & 7;
  const float* src = W + (size_t)n * 2048 + 1024 + g * 8;
  const float4 f0 = *reinterpret_cast<const float4*>(src);
  const float4 f1 = *reinterpret_cast<const float4*>(src + 4);
  uint4 u = make_uint4(cvt2(f0.x, f0.y), cvt2(f0.z, f0.w),
                       cvt2(f1.x, f1.y), cvt2(f1.z, f1.w));
  const int nblk = n >> 7, row = n & 127;
  const size_t off = ((size_t)(nblk * 16 + kt) * 128 + row) * 128 +
                     (size_t)(gi ^ (row & 7)) * 16;
  *reinterpret_cast<uint4*>(w2s + off) = u;
}

__device__ __forceinline__ void a_body(const float* __restrict__ hidden,
                                       const float* __restrict__ W,
                                       const float* __restrict__ bias,
                                       float* __restrict__ A, float* hl,
                                       int bx, int tid) {
  const int hc = bx & 3, b = bx >> 2;
  *reinterpret_cast<float4*>(&hl[tid * 4]) =
      *reinterpret_cast<const float4*>(hidden + (size_t)b * HDIM + tid * 4);
  __syncthreads();
  const int h = hc * 256 + tid;
  const float* wr = W + (size_t)h * 2048;
  float a0 = 0.f, a1 = 0.f, a2 = 0.f, a3 = 0.f;
  for (int k = 0; k < HDIM; k += 16) {
    const float4 w0 = *reinterpret_cast<const float4*>(wr + k);
    const float4 w1 = *reinterpret_cast<const float4*>(wr + k + 4);
    const float4 w2 = *reinterpret_cast<const float4*>(wr + k + 8);
    const float4 w3 = *reinterpret_cast<const float4*>(wr + k + 12);
    a0 += w0.x * hl[k]      + w0.y * hl[k + 1]  + w0.z * hl[k + 2]  + w0.w * hl[k + 3];
    a1 += w1.x * hl[k + 4]  + w1.y * hl[k + 5]  + w1.z * hl[k + 6]  + w1.w * hl[k + 7];
    a2 += w2.x * hl[k + 8]  + w2.y * hl[k + 9]  + w2.z * hl[k + 10] + w2.w * hl[k + 11];
    a3 += w3.x * hl[k + 12] + w3.y * hl[k + 13] + w3.z * hl[k + 14] + w3.w * hl[k + 15];
  }
  A[(size_t)b * HDIM + h] = bias[h] + ((a0 + a1) + (a2 + a3));
}

// ---- small prep: [0,512) W2 tiles | [512,768) A ----
__global__ __launch_bounds__(256) void prep_small_kernel(const float* __restrict__ W,
                                                         const float* __restrict__ hidden,
                                                         const float* __restrict__ bias,
                                                         char* __restrict__ w2s,
                                                         float* __restrict__ A) {
  __shared__ float hl[HDIM];
  const int bid = blockIdx.x;
  const int tid = threadIdx.x;
  if (bid < 512) w2_body(W, w2s, bid, tid);
  else a_body(hidden, W, bias, A, hl, bid - 512, tid);
}

// ---- main GEMM, conversion fused, repaired cover:
//      256x256 tile, 8 waves, BK=64, dbuf; per K-tile: issue ALL staging at ph0
//      (8 A f32 loads + 4 B DMAs), cvt+ds_write A at ph3 (overlapped), one
//      __syncthreads per K-tile (B DMAs get full 4-phase cover). ----
__global__ __launch_bounds__(512, 2) void gemm8f2_kernel(const float* __restrict__ enc,
                                                         const char* __restrict__ w2s,
                                                         const float* __restrict__ A,
                                                         const float* __restrict__ v,
                                                         float* __restrict__ sp) {
  __shared__ __align__(16) unsigned short As[2][2][128][64];  // 64 KB
  __shared__ __align__(16) unsigned short Bs[2][2][128][64];  // 64 KB
  __shared__ float red4[4][256];                              // 4 KB

  const int bid = blockIdx.x;
  const int lg = (bid & 7) * 64 + (bid >> 3);  // XCD swizzle, 512 % 8 == 0
  const int nblk = lg & 3, mstrip = lg >> 2;
  const int m0 = mstrip * 256, n0 = nblk * 256;
  const int b = m0 >> 9;

  const int tid = threadIdx.x;
  const int w = tid >> 6, l = tid & 63;
  const int wm = w >> 2, wn = w & 3;  // 2 x 4 wave grid
  const int lr = l & 15, lk = l >> 4;

  f32x4 acc[8][4];
#pragma unroll
  for (int i = 0; i < 8; ++i)
#pragma unroll
    for (int j = 0; j < 4; ++j) acc[i][j] = (f32x4){0.f, 0.f, 0.f, 0.f};

  // A staging geometry: thread -> (row0 + i*64, granule g0)
  const int row0 = tid >> 3, g0 = tid & 7;
  const float* encA = enc + (size_t)m0 * HDIM + g0 * 8;
  const char* bT0 = w2s + (size_t)((nblk * 2 + 0) * 16) * 16384;
  const char* bT1 = w2s + (size_t)((nblk * 2 + 1) * 16) * 16384;
  const int wbase = w * 1024;
  const int lofs = l * 16;

#define STAGE_B(srcp, dstp)                                                \
  do {                                                                     \
    gld_lds16((const char*)(srcp) + wbase + lofs, (char*)(dstp) + wbase);  \
    gld_lds16((const char*)(srcp) + 8192 + wbase + lofs,                   \
              (char*)(dstp) + 8192 + wbase);                               \
  } while (0)
#define LOAD_A(pfv, ii, ktv)                                                 \
  do {                                                                      \
    const float* s_ = encA + (size_t)(row0 + (ii) * 64) * HDIM + (ktv) * 64; \
    pfv[2 * (ii)]     = *reinterpret_cast<const float4*>(s_);               \
    pfv[2 * (ii) + 1] = *reinterpret_cast<const float4*>(s_ + 4);           \
  } while (0)
// convert pf (one K-tile of A) and write to swizzled slots of dstbuf[2][128][64]
#define CVT_WRITE(dstbuf)                                                    \
  do {                                                                      \
    _Pragma("unroll")                                                       \
    for (int i_ = 0; i_ < 4; ++i_) {                                        \
      const int row_ = row0 + i_ * 64;                                      \
      uint4 u_ = make_uint4(cvt2(pf[2 * i_].x, pf[2 * i_].y),               \
                            cvt2(pf[2 * i_].z, pf[2 * i_].w),               \
                            cvt2(pf[2 * i_ + 1].x, pf[2 * i_ + 1].y),       \
                            cvt2(pf[2 * i_ + 1].z, pf[2 * i_ + 1].w));      \
      char* dst_ = (char*)&(dstbuf)[row_ >> 7][0][0];                       \
      *reinterpret_cast<uint4*>(dst_ + (row_ & 127) * 128 +                 \
                                ((g0 ^ (row_ & 7)) * 16)) = u_;             \
    }                                                                       \
  } while (0)
#define VMW4 do { asm volatile("s_waitcnt vmcnt(4)" ::: "memory"); \
                  __builtin_amdgcn_sched_barrier(0); } while (0)
#define LGKM0 do { asm volatile("s_waitcnt lgkmcnt(0)" ::: "memory"); \
                   __builtin_amdgcn_sched_barrier(0); } while (0)

  float4 pf[8];

  // ---- prologue: stage K-tile 0 ----
  LOAD_A(pf, 0, 0); LOAD_A(pf, 1, 0); LOAD_A(pf, 2, 0); LOAD_A(pf, 3, 0);  // vm 1-8
  STAGE_B(bT0, &Bs[0][0][0][0]);                                           // vm 9-10
  STAGE_B(bT1, &Bs[0][1][0][0]);                                           // vm 11-12
  VMW4;               // A loads done; 4 B DMAs outstanding
  CVT_WRITE(As[0]);

  const int gax = lr & 7;

  for (int kt = 0; kt < 16; ++kt) {
    const int cur = kt & 1, nxt = cur ^ 1;
    __syncthreads();  // drains: B(kt) DMAs (4-phase cover), As writes visible,
                      // and certifies all waves done reading buffers [nxt]
    const bool pfb = (kt < 15);
    const char* Ah = (const char*)&As[cur][wm][0][0];
    const char* Bh = (const char*)&Bs[cur][wn >> 1][0][0];
    const int brow0 = (wn & 1) * 64;
    const int gq0 = (lk ^ gax) * 16;
    const int gq1 = ((4 + lk) ^ gax) * 16;

    short8 af[4], bf[4];

    // ---- ph0: issue ALL staging for kt+1, then MFMA quadrant (gq0, rows 0-63)
    if (pfb) {
      LOAD_A(pf, 0, kt + 1); LOAD_A(pf, 1, kt + 1);
      LOAD_A(pf, 2, kt + 1); LOAD_A(pf, 3, kt + 1);          // vm 1-8
      STAGE_B(bT0 + (size_t)(kt + 1) * 16384, &Bs[nxt][0][0][0]);  // vm 9-10
      STAGE_B(bT1 + (size_t)(kt + 1) * 16384, &Bs[nxt][1][0][0]);  // vm 11-12
    }
#pragma unroll
    for (int f = 0; f < 4; ++f) {
      bf[f] = *reinterpret_cast<const short8*>(Bh + (brow0 + f * 16 + lr) * 128 + gq0);
      af[f] = *reinterpret_cast<const short8*>(Ah + (f * 16 + lr) * 128 + gq0);
    }
    LGKM0;
    __builtin_amdgcn_s_setprio(1);
#pragma unroll
    for (int fm = 0; fm < 4; ++fm)
#pragma unroll
      for (int fn = 0; fn < 4; ++fn)
        acc[fm][fn] = __builtin_amdgcn_mfma_f32_16x16x32_bf16(af[fm], bf[fn], acc[fm][fn], 0, 0, 0);
    __builtin_amdgcn_s_setprio(0);

    // ---- ph1: rows 64-127, gq0
#pragma unroll
    for (int f = 0; f < 4; ++f)
      af[f] = *reinterpret_cast<const short8*>(Ah + (64 + f * 16 + lr) * 128 + gq0);
    LGKM0;
    __builtin_amdgcn_s_setprio(1);
#pragma unroll
    for (int fm = 0; fm < 4; ++fm)
#pragma unroll
      for (int fn = 0; fn < 4; ++fn)
        acc[4 + fm][fn] = __builtin_amdgcn_mfma_f32_16x16x32_bf16(af[fm], bf[fn], acc[4 + fm][fn], 0, 0, 0);
    __builtin_amdgcn_s_setprio(0);

    // ---- ph2: rows 0-63, gq1
#pragma unroll
    for (int f = 0; f < 4; ++f) {
      bf[f] = *reinterpret_cast<const short8*>(Bh + (brow0 + f * 16 + lr) * 128 + gq1);
      af[f] = *reinterpret_cast<const short8*>(Ah + (f * 16 + lr) * 128 + gq1);
    }
    LGKM0;
    __builtin_amdgcn_s_setprio(1);
#pragma unroll
    for (int fm = 0; fm < 4; ++fm)
#pragma unroll
      for (int fn = 0; fn < 4; ++fn)
        acc[fm][fn] = __builtin_amdgcn_mfma_f32_16x16x32_bf16(af[fm], bf[fn], acc[fm][fn], 0, 0, 0);
    __builtin_amdgcn_s_setprio(0);

    // ---- ph3: cvt+write A(kt+1) into As[nxt] (overlapped), then rows 64-127, gq1
    if (pfb) {
      VMW4;               // A-loads for kt+1 done (B DMAs still in flight)
      CVT_WRITE(As[nxt]); // safe: all waves past the kt barrier read only [cur]
    }
#pragma unroll
    for (int f = 0; f < 4; ++f)
      af[f] = *reinterpret_cast<const short8*>(Ah + (64 + f * 16 + lr) * 128 + gq1);
    LGKM0;
    __builtin_amdgcn_s_setprio(1);
#pragma unroll
    for (int fm = 0; fm < 4; ++fm)
#pragma unroll
      for (int fn = 0; fn < 4; ++fn)
        acc[4 + fm][fn] = __builtin_amdgcn_mfma_f32_16x16x32_bf16(af[fm], bf[fn], acc[4 + fm][fn], 0, 0, 0);
    __builtin_amdgcn_s_setprio(0);
  }
#undef STAGE_B
#undef LOAD_A
#undef CVT_WRITE
#undef VMW4
#undef LGKM0

  // ---- epilogue: partial[m] = sum_n v[n] * tanh(C[m,n] + A[b,n]) ----
  float a_n[4], v_n[4];
#pragma unroll
  for (int fn = 0; fn < 4; ++fn) {
    const int n = wn * 64 + fn * 16 + lr;
    a_n[fn] = A[(size_t)b * HDIM + n0 + n];
    v_n[fn] = v[n0 + n];
  }
#pragma unroll
  for (int fm8 = 0; fm8 < 8; ++fm8) {
#pragma unroll
    for (int r = 0; r < 4; ++r) {
      float s = 0.f;
#pragma unroll
      for (int fn = 0; fn < 4; ++fn)
        s += v_n[fn] * fast_tanh(acc[fm8][fn][r] + a_n[fn]);
      s += __shfl_xor(s, 1);
      s += __shfl_xor(s, 2);
      s += __shfl_xor(s, 4);
      s += __shfl_xor(s, 8);
      if (lr == 0) red4[wn][wm * 128 + fm8 * 16 + lk * 4 + r] = s;
    }
  }
  __syncthreads();
  if (tid < 256) {
    const float ssum = red4[0][tid] + red4[1][tid] + red4[2][tid] + red4[3][tid];
    sp[(size_t)nblk * MTOT + m0 + tid] = ssum;
  }
}

// ---- softmax over s (512) per b; sums 4 partials ----
__global__ __launch_bounds__(512) void softmax4_kernel(const float* __restrict__ sp,
                                                       float* __restrict__ wts) {
  const int b = blockIdx.x, s = threadIdx.x;
  float sc = 0.f;
#pragma unroll
  for (int j = 0; j < 4; ++j) sc += sp[(size_t)j * MTOT + b * SDIM + s];
  float m = sc;
#pragma unroll
  for (int d = 1; d < 64; d <<= 1) m = fmaxf(m, __shfl_xor(m, d));
  __shared__ float redm[8], reds[8];
  if ((s & 63) == 0) redm[s >> 6] = m;
  __syncthreads();
  m = redm[0];
#pragma unroll
  for (int j = 1; j < 8; ++j) m = fmaxf(m, redm[j]);
  const float e = expf(sc - m);
  float sum = e;
#pragma unroll
  for (int d = 1; d < 64; d <<= 1) sum += __shfl_xor(sum, d);
  if ((s & 63) == 0) reds[s >> 6] = sum;
  __syncthreads();
  float tot = 0.f;
#pragma unroll
  for (int j = 0; j < 8; ++j) tot += reds[j];
  wts[(size_t)b * SDIM + s] = e / tot;
}

// ---- context[b,h] = sum_s w[b,s]*enc[b,s,h]; float2/lane ----
__global__ __launch_bounds__(256) void context_kernel(const float* __restrict__ enc,
                                                      const float* __restrict__ wts,
                                                      float* __restrict__ ctx) {
  const int hc = blockIdx.x;  // 0..1
  const int b  = blockIdx.y;  // 0..63
  const int t  = threadIdx.x;
  __shared__ float wl[SDIM];
  wl[t] = wts[(size_t)b * SDIM + t];
  wl[t + 256] = wts[(size_t)b * SDIM + 256 + t];
  __syncthreads();
  const int h = hc * 512 + t * 2;
  const float* e0 = enc + (size_t)b * SDIM * HDIM + h;
  float x0 = 0.f, y0 = 0.f, x1 = 0.f, y1 = 0.f;
  for (int s = 0; s < SDIM; s += 2) {
    const float2 v0 = *reinterpret_cast<const float2*>(e0 + (size_t)s * HDIM);
    const float2 v1 = *reinterpret_cast<const float2*>(e0 + (size_t)(s + 1) * HDIM);
    x0 += wl[s] * v0.x;     y0 += wl[s] * v0.y;
    x1 += wl[s + 1] * v1.x; y1 += wl[s + 1] * v1.y;
  }
  ctx[(size_t)b * HDIM + h]     = x0 + x1;
  ctx[(size_t)b * HDIM + h + 1] = y0 + y1;
}

extern "C" void kernel_launch(void* const* d_in, const int* in_sizes, int n_in,
                              void* d_out, int out_size, void* d_ws, size_t ws_size,
                              hipStream_t stream) {
  const float* hidden = (const float*)d_in[0];
  const float* enc    = (const float*)d_in[1];
  const float* W      = (const float*)d_in[2];
  const float* bias   = (const float*)d_in[3];
  const float* v      = (const float*)d_in[4];

  float* ctx = (float*)d_out;                // [64*1024] context
  float* wts = (float*)d_out + BDIM * HDIM;  // [64*512] attention weights

  char* ws = (char*)d_ws;
  char* w2s = ws;                                                   // 2 MB swizzled W2 tiles
  float* A  = (float*)(ws + (size_t)2 * 1024 * 1024);               // 256 KB
  float* sp = (float*)(ws + (size_t)2 * 1024 * 1024 + 256 * 1024);  // 512 KB (4 partials)

  hipLaunchKernelGGL(prep_small_kernel, dim3(768), dim3(256), 0, stream,
                     W, hidden, bias, w2s, A);
  hipLaunchKernelGGL(gemm8f2_kernel, dim3(512), dim3(512), 0, stream, enc, w2s, A, v, sp);
  hipLaunchKernelGGL(softmax4_kernel, dim3(64), dim3(512), 0, stream, sp, wts);
  hipLaunchKernelGGL(context_kernel, dim3(2, 64), dim3(256), 0, stream, enc, wts, ctx);
}